// Round 2
// baseline (378.108 us; speedup 1.0000x reference)
//
#include <hip/hip_runtime.h>

#define NSEG 512
#define NSPLIT 32

typedef __attribute__((ext_vector_type(8))) short short8;
typedef __attribute__((ext_vector_type(4))) short short4v;
typedef __attribute__((ext_vector_type(4))) float floatx4;

// ws layout (bytes), all 16B-aligned
#define WS_WAT   0        // short [256][32]   WA^T
#define WS_WBT2  16384    // short [256][64]   WB^T (K padded 48->64 w/ zeros)
#define WS_W2GA  49152    // short [256][256]  (gA*Wback)^T
#define WS_W2GB  180224   // short [256][256]  (gB*Wback)^T
#define WS_C1A   311296   // float[256] gA . Wback[:,n]
#define WS_C2A   312320   // float[256] betaA . Wback[:,n] + bback
#define WS_C1B   313344
#define WS_C2B   314368
#define WS_INVA  315392   // float[32]  1/stdA
#define WS_INVB  315520   // float[48]  1/stdB
#define WS_VPART 315712   // float [NSPLIT][NSEG]
#define WS_CPART 381248   // float [NSPLIT][NSEG]
// end 446784

__device__ __forceinline__ short f2bf(float f) {  // RNE
  unsigned u = __builtin_bit_cast(unsigned, f);
  u += 0x7FFFu + ((u >> 16) & 1u);
  return (short)(u >> 16);
}

__global__ void prep_kernel(const float* __restrict__ WA, const float* __restrict__ WB,
                            const float* __restrict__ Wback,
                            const float* __restrict__ gA, const float* __restrict__ betaA,
                            const float* __restrict__ gB, const float* __restrict__ betaB,
                            const float* __restrict__ bback,
                            const float* __restrict__ sA, const float* __restrict__ sB,
                            char* __restrict__ ws) {
  short* waT  = (short*)(ws + WS_WAT);
  short* wbT2 = (short*)(ws + WS_WBT2);
  short* w2gA = (short*)(ws + WS_W2GA);
  short* w2gB = (short*)(ws + WS_W2GB);
  float* c1A = (float*)(ws + WS_C1A);
  float* c2A = (float*)(ws + WS_C2A);
  float* c1B = (float*)(ws + WS_C1B);
  float* c2B = (float*)(ws + WS_C2B);
  float* invA = (float*)(ws + WS_INVA);
  float* invB = (float*)(ws + WS_INVB);
  float* vz   = (float*)(ws + WS_VPART);
  int tid = blockIdx.x * blockDim.x + threadIdx.x;
  int stride = gridDim.x * blockDim.x;
  // output-indexed (coalesced writes); strided reads are L2-absorbed
  for (int i = tid; i < 32*256; i += stride) {          // waT[n][k] = WA[k][n]
    int n = i >> 5, k = i & 31;
    waT[i] = f2bf(WA[k*256 + n]);
  }
  for (int i = tid; i < 256*64; i += stride) {          // wbT2[n][k] = WB[k][n], pad K
    int n = i >> 6, k = i & 63;
    wbT2[i] = (k < 48) ? f2bf(WB[k*256 + n]) : (short)0;
  }
  for (int i = tid; i < 256*256; i += stride) {         // w2g[n][k] = g[k]*Wback[k][n]
    int n = i >> 8, k = i & 255;
    float w = Wback[k*256 + n];
    w2gA[i] = f2bf(gA[k] * w);
    w2gB[i] = f2bf(gB[k] * w);
  }
  // c1/c2: 4-way block-parallel (one coefficient vector per block)
  if (blockIdx.x < 4 && threadIdx.x < 256) {
    int n = threadIdx.x;
    int which = blockIdx.x;
    const float* coef = (which == 0) ? gA : (which == 1) ? betaA : (which == 2) ? gB : betaB;
    float a = 0.f;
    #pragma unroll 8
    for (int k = 0; k < 256; k++) a = fmaf(coef[k], Wback[k*256 + n], a);
    if (which == 0)      c1A[n] = a;
    else if (which == 1) c2A[n] = a + bback[n];
    else if (which == 2) c1B[n] = a;
    else                 c2B[n] = a + bback[n];
  }
  if (tid < 32) invA[tid] = 1.0f / sA[tid];
  if (tid < 48) invB[tid] = 1.0f / sB[tid];
  for (int i = tid; i < 2*NSPLIT*NSEG; i += stride) vz[i] = 0.0f;  // vpart+cpart
}

// 512 threads / 8 waves per block; wave w owns cols [32w, 32w+32) of a 64-row tile.
// Per-wave acc is [4 mt][2 nt] = 32 VGPRs -> whole kernel fits the <=128-reg
// 4-waves/SIMD tier with NO scratch spill (round-1 spilled ~16 regs/thread,
// visible as +118 MB WRITE_SIZE).
// Operand-swapped MFMA: mfma(W_frag, h_frag) => lane's 4 acc regs are 4
// CONSECUTIVE cols of one row: row = 16*mt + l15, col = 32*w + 16*nt + 4*quad + r.
__global__ __launch_bounds__(512, 4) void fused_kernel(
    const float* __restrict__ featsA, const float* __restrict__ featsB,
    const float* __restrict__ mA, const float* __restrict__ mB,
    const float* __restrict__ bA, const float* __restrict__ bB,
    const float* __restrict__ Wv, const int* __restrict__ bidx,
    const char* __restrict__ ws, float* __restrict__ vpart, float* __restrict__ cpart,
    int tilesA, int nA, int nB)
{
  __shared__ __attribute__((aligned(16))) short ztile[64*264];   // h, bf16, stride 264
  __shared__ __attribute__((aligned(16))) float sred[64][8];
  __shared__ __attribute__((aligned(16))) float s2red[64][8];
  __shared__ __attribute__((aligned(16))) float vpw[64][8];

  const int tid  = threadIdx.x;
  const int wave = tid >> 6;
  const int lane = tid & 63;
  const int l15  = lane & 15;
  const int quad = lane >> 4;

  const bool isA = (blockIdx.x < (unsigned)tilesA);
  const int  tb  = isA ? blockIdx.x : (blockIdx.x - tilesA);
  const int  r0  = tb * 64;
  const int  nrows = isA ? nA : nB;
  const int  valid = min(64, nrows - r0);
  const float* feats = isA ? featsA : featsB;
  const float* meanp = isA ? mA : mB;
  const float* invp  = (const float*)(ws + (isA ? WS_INVA : WS_INVB));
  const float* biasp = isA ? bA : bB;
  const short* weT   = (const short*)(ws + (isA ? WS_WAT : WS_WBT2));
  const short* w2gT  = (const short*)(ws + (isA ? WS_W2GA : WS_W2GB));
  const float* c1p   = (const float*)(ws + (isA ? WS_C1A : WS_C1B));
  const float* c2p   = (const float*)(ws + (isA ? WS_C2A : WS_C2B));
  const int f       = isA ? 32 : 48;
  const int kstride = isA ? 32 : 64;
  const int ksteps  = isA ? 1 : 2;

  // ---- GEMM1: h = relu(norm(feats) @ W1 + b1), A-frags straight from global ----
  floatx4 acc1[4][2];
  #pragma unroll
  for (int mt = 0; mt < 4; mt++)
    #pragma unroll
    for (int nt = 0; nt < 2; nt++)
      acc1[mt][nt] = 0.0f;

  for (int kk = 0; kk < ksteps; kk++) {
    const int k0 = kk*32 + quad*8;
    const bool kvalid = (k0 < f);
    floatx4 mv0 = {0,0,0,0}, mv1 = {0,0,0,0}, iv0 = {1,1,1,1}, iv1 = {1,1,1,1};
    if (kvalid) {
      mv0 = *(const floatx4*)(meanp + k0);  mv1 = *(const floatx4*)(meanp + k0 + 4);
      iv0 = *(const floatx4*)(invp + k0);   iv1 = *(const floatx4*)(invp + k0 + 4);
    }
    short8 af[4];
    #pragma unroll
    for (int mt = 0; mt < 4; mt++) {
      short8 a = {0,0,0,0,0,0,0,0};
      int row = 16*mt + l15;
      if (kvalid && row < valid) {
        const float* fp = feats + (size_t)(r0 + row) * f + k0;
        floatx4 x0 = *(const floatx4*)fp;
        floatx4 x1 = *(const floatx4*)(fp + 4);
        #pragma unroll
        for (int e = 0; e < 4; e++) {
          float h0 = (x0[e] - mv0[e]) * iv0[e];
          h0 = fminf(fmaxf(h0, -5.0f), 5.0f);
          a[e] = f2bf(h0);
          float h1 = (x1[e] - mv1[e]) * iv1[e];
          h1 = fminf(fmaxf(h1, -5.0f), 5.0f);
          a[4+e] = f2bf(h1);
        }
      }
      af[mt] = a;
    }
    short8 bfw[2];
    #pragma unroll
    for (int nt = 0; nt < 2; nt++)
      bfw[nt] = *(const short8*)(weT + (size_t)(32*wave + 16*nt + l15) * kstride + kk*32 + quad*8);
    #pragma unroll
    for (int mt = 0; mt < 4; mt++)
      #pragma unroll
      for (int nt = 0; nt < 2; nt++)
        acc1[mt][nt] = __builtin_amdgcn_mfma_f32_16x16x32_bf16(bfw[nt], af[mt], acc1[mt][nt], 0, 0, 0);
  }

  // ---- epilogue1: h=relu(.+b1) -> ztile (bf16, b64 packed) + per-row stats ----
  float sacc[4], s2acc[4];
  #pragma unroll
  for (int mt = 0; mt < 4; mt++) { sacc[mt] = 0.f; s2acc[mt] = 0.f; }

  #pragma unroll
  for (int nt = 0; nt < 2; nt++) {
    const int c0 = 32*wave + 16*nt + 4*quad;
    floatx4 b1v = *(const floatx4*)(biasp + c0);
    #pragma unroll
    for (int mt = 0; mt < 4; mt++) {
      short4v pk;
      #pragma unroll
      for (int r = 0; r < 4; r++) {
        float h = fmaxf(acc1[mt][nt][r] + b1v[r], 0.0f);
        sacc[mt] += h;
        s2acc[mt] = fmaf(h, h, s2acc[mt]);
        pk[r] = f2bf(h);
      }
      *(short4v*)(ztile + (16*mt + l15)*264 + c0) = pk;
    }
  }
  // reduce stats over the 4 quads (cols); rows are lane-local
  #pragma unroll
  for (int mt = 0; mt < 4; mt++) {
    float s = sacc[mt], s2 = s2acc[mt];
    s += __shfl_xor(s, 16, 64);  s2 += __shfl_xor(s2, 16, 64);
    s += __shfl_xor(s, 32, 64);  s2 += __shfl_xor(s2, 32, 64);
    if (lane < 16) {
      sred[16*mt + lane][wave] = s;
      s2red[16*mt + lane][wave] = s2;
    }
  }
  __syncthreads();

  // ---- per-row LN scalars (row = 16*mt + l15) ----
  float rsv[4], mrsv[4];
  #pragma unroll
  for (int mt = 0; mt < 4; mt++) {
    int row = 16*mt + l15;
    floatx4 sv0  = *(const floatx4*)&sred[row][0];
    floatx4 sv1  = *(const floatx4*)&sred[row][4];
    floatx4 s2v0 = *(const floatx4*)&s2red[row][0];
    floatx4 s2v1 = *(const floatx4*)&s2red[row][4];
    float s  = (sv0[0]+sv0[1]+sv0[2]+sv0[3]) + (sv1[0]+sv1[1]+sv1[2]+sv1[3]);
    float s2 = (s2v0[0]+s2v0[1]+s2v0[2]+s2v0[3]) + (s2v1[0]+s2v1[1]+s2v1[2]+s2v1[3]);
    float mu  = s * (1.0f/256.0f);
    float var = fmaxf(s2 * (1.0f/256.0f) - mu*mu, 0.0f);
    float rs  = rsqrtf(var + 1e-5f);
    rsv[mt]  = rs;
    mrsv[mt] = mu * rs;
  }

  // ---- GEMM2: q = h @ (g*Wback), K=256 ----
  floatx4 acc2[4][2];
  #pragma unroll
  for (int mt = 0; mt < 4; mt++)
    #pragma unroll
    for (int nt = 0; nt < 2; nt++)
      acc2[mt][nt] = 0.0f;

  #pragma unroll
  for (int kk = 0; kk < 8; kk++) {
    short8 bf[2];
    #pragma unroll
    for (int nt = 0; nt < 2; nt++)
      bf[nt] = *(const short8*)(w2gT + (size_t)(32*wave + 16*nt + l15)*256 + kk*32 + quad*8);
    short8 af[4];
    #pragma unroll
    for (int mt = 0; mt < 4; mt++)
      af[mt] = *(const short8*)(ztile + (16*mt + l15)*264 + kk*32 + quad*8);
    #pragma unroll
    for (int mt = 0; mt < 4; mt++)
      #pragma unroll
      for (int nt = 0; nt < 2; nt++)
        acc2[mt][nt] = __builtin_amdgcn_mfma_f32_16x16x32_bf16(bf[nt], af[mt], acc2[mt][nt], 0, 0, 0);
  }

  // ---- epilogue2: y = relu(rs*q - mu*rs*c1 + c2); v = y . Wv ----
  float pv[4] = {0.f, 0.f, 0.f, 0.f};
  #pragma unroll
  for (int nt = 0; nt < 2; nt++) {
    const int c0 = 32*wave + 16*nt + 4*quad;
    floatx4 c1v = *(const floatx4*)(c1p + c0);
    floatx4 c2v = *(const floatx4*)(c2p + c0);
    floatx4 wvv = *(const floatx4*)(Wv + c0);
    #pragma unroll
    for (int mt = 0; mt < 4; mt++) {
      float rs = rsv[mt], mrs = mrsv[mt];
      #pragma unroll
      for (int r = 0; r < 4; r++) {
        float t = fmaf(-mrs, c1v[r], c2v[r]);
        float y = fmaf(rs, acc2[mt][nt][r], t);
        y = fmaxf(y, 0.0f);
        pv[mt] = fmaf(y, wvv[r], pv[mt]);
      }
    }
  }
  #pragma unroll
  for (int mt = 0; mt < 4; mt++) {
    float p = pv[mt];
    p += __shfl_xor(p, 16, 64);
    p += __shfl_xor(p, 32, 64);
    if (lane < 16) vpw[16*mt + lane][wave] = p;
  }
  __syncthreads();

  // ---- scatter ----
  if (tid < valid) {
    floatx4 v0 = *(const floatx4*)&vpw[tid][0];
    floatx4 v1 = *(const floatx4*)&vpw[tid][4];
    float v = (v0[0]+v0[1]+v0[2]+v0[3]) + (v1[0]+v1[1]+v1[2]+v1[3]);
    int g = (isA ? r0 : (nA + r0)) + tid;
    int seg = bidx[g];
    int split = blockIdx.x & (NSPLIT - 1);
    atomicAdd(&vpart[split*NSEG + seg], v);
    atomicAdd(&cpart[split*NSEG + seg], 1.0f);
  }
}

__global__ void final_kernel(const float* __restrict__ vpart, const float* __restrict__ cpart,
                             const float* __restrict__ bv, float* __restrict__ out, int nseg) {
  int s = blockIdx.x * blockDim.x + threadIdx.x;
  if (s < nseg) {
    float a = 0.0f, c = 0.0f;
    #pragma unroll 8
    for (int i = 0; i < NSPLIT; i++) { a += vpart[i*NSEG + s]; c += cpart[i*NSEG + s]; }
    out[s] = a / fmaxf(c, 1.0f) + bv[0];
  }
}

extern "C" void kernel_launch(void* const* d_in, const int* in_sizes, int n_in,
                              void* d_out, int out_size, void* d_ws, size_t ws_size,
                              hipStream_t stream) {
  const float* featsA = (const float*)d_in[0];
  const float* featsB = (const float*)d_in[1];
  const float* mA     = (const float*)d_in[2];
  const float* sA     = (const float*)d_in[3];
  const float* mB     = (const float*)d_in[4];
  const float* sB     = (const float*)d_in[5];
  const float* WA     = (const float*)d_in[6];
  const float* bA     = (const float*)d_in[7];
  const float* gA     = (const float*)d_in[8];
  const float* betaA  = (const float*)d_in[9];
  const float* WB     = (const float*)d_in[10];
  const float* bB     = (const float*)d_in[11];
  const float* gB     = (const float*)d_in[12];
  const float* betaB  = (const float*)d_in[13];
  const float* Wback  = (const float*)d_in[14];
  const float* bback  = (const float*)d_in[15];
  const float* Wv     = (const float*)d_in[16];
  const float* bv     = (const float*)d_in[17];
  const int*   bidx   = (const int*)d_in[18];

  const int nA = in_sizes[0] / 32;
  const int nB = in_sizes[1] / 48;
  char* ws = (char*)d_ws;
  float* vpart = (float*)(ws + WS_VPART);
  float* cpart = (float*)(ws + WS_CPART);
  float* out = (float*)d_out;

  prep_kernel<<<256, 256, 0, stream>>>(WA, WB, Wback, gA, betaA, gB, betaB,
                                       bback, sA, sB, ws);

  const int tilesA = (nA + 63) / 64;
  const int tilesB = (nB + 63) / 64;
  fused_kernel<<<tilesA + tilesB, 512, 0, stream>>>(
      featsA, featsB, mA, mB, bA, bB, Wv, bidx, ws, vpart, cpart, tilesA, nA, nB);

  final_kernel<<<(out_size + 255) / 256, 256, 0, stream>>>(vpart, cpart, bv, out, out_size);
}

// Round 3
// 307.283 us; speedup vs baseline: 1.2305x; 1.2305x over previous
//
#include <hip/hip_runtime.h>

#define NSEG 512
#define NSPLIT 32

typedef __attribute__((ext_vector_type(8))) short short8;
typedef __attribute__((ext_vector_type(4))) short short4v;
typedef __attribute__((ext_vector_type(4))) float floatx4;

// ws layout (bytes), all 16B-aligned
#define WS_WAT   0        // short [256][32]   WA^T
#define WS_WBT2  16384    // short [256][64]   WB^T (K padded 48->64 w/ zeros)
#define WS_W2GA  49152    // short [256][256]  (gA*Wback)^T
#define WS_W2GB  180224   // short [256][256]  (gB*Wback)^T
#define WS_C1A   311296   // float[256] gA . Wback[:,n]
#define WS_C2A   312320   // float[256] betaA . Wback[:,n] + bback
#define WS_C1B   313344
#define WS_C2B   314368
#define WS_INVA  315392   // float[32]  1/stdA
#define WS_INVB  315520   // float[48]  1/stdB
#define WS_VPART 315712   // float [NSPLIT][NSEG]
#define WS_CPART 381248   // float [NSPLIT][NSEG]
// end 446784

__device__ __forceinline__ short f2bf(float f) {  // RNE
  unsigned u = __builtin_bit_cast(unsigned, f);
  u += 0x7FFFu + ((u >> 16) & 1u);
  return (short)(u >> 16);
}

__global__ void prep_kernel(const float* __restrict__ WA, const float* __restrict__ WB,
                            const float* __restrict__ Wback,
                            const float* __restrict__ gA, const float* __restrict__ betaA,
                            const float* __restrict__ gB, const float* __restrict__ betaB,
                            const float* __restrict__ bback,
                            const float* __restrict__ sA, const float* __restrict__ sB,
                            char* __restrict__ ws) {
  short* waT  = (short*)(ws + WS_WAT);
  short* wbT2 = (short*)(ws + WS_WBT2);
  short* w2gA = (short*)(ws + WS_W2GA);
  short* w2gB = (short*)(ws + WS_W2GB);
  float* c1A = (float*)(ws + WS_C1A);
  float* c2A = (float*)(ws + WS_C2A);
  float* c1B = (float*)(ws + WS_C1B);
  float* c2B = (float*)(ws + WS_C2B);
  float* invA = (float*)(ws + WS_INVA);
  float* invB = (float*)(ws + WS_INVB);
  float* vz   = (float*)(ws + WS_VPART);
  int tid = blockIdx.x * blockDim.x + threadIdx.x;
  int stride = gridDim.x * blockDim.x;
  // output-indexed (coalesced writes); strided reads are L2-absorbed
  for (int i = tid; i < 32*256; i += stride) {          // waT[n][k] = WA[k][n]
    int n = i >> 5, k = i & 31;
    waT[i] = f2bf(WA[k*256 + n]);
  }
  for (int i = tid; i < 256*64; i += stride) {          // wbT2[n][k] = WB[k][n], pad K
    int n = i >> 6, k = i & 63;
    wbT2[i] = (k < 48) ? f2bf(WB[k*256 + n]) : (short)0;
  }
  for (int i = tid; i < 256*256; i += stride) {         // w2g[n][k] = g[k]*Wback[k][n]
    int n = i >> 8, k = i & 255;
    float w = Wback[k*256 + n];
    w2gA[i] = f2bf(gA[k] * w);
    w2gB[i] = f2bf(gB[k] * w);
  }
  // c1/c2: 4-way block-parallel (one coefficient vector per block)
  if (blockIdx.x < 4 && threadIdx.x < 256) {
    int n = threadIdx.x;
    int which = blockIdx.x;
    const float* coef = (which == 0) ? gA : (which == 1) ? betaA : (which == 2) ? gB : betaB;
    float a = 0.f;
    #pragma unroll 8
    for (int k = 0; k < 256; k++) a = fmaf(coef[k], Wback[k*256 + n], a);
    if (which == 0)      c1A[n] = a;
    else if (which == 1) c2A[n] = a + bback[n];
    else if (which == 2) c1B[n] = a;
    else                 c2B[n] = a + bback[n];
  }
  if (tid < 32) invA[tid] = 1.0f / sA[tid];
  if (tid < 48) invB[tid] = 1.0f / sB[tid];
  for (int i = tid; i < 2*NSPLIT*NSEG; i += stride) vz[i] = 0.0f;  // vpart+cpart
}

// 256 threads / 4 waves; wave owns cols [64w, 64w+64) of a 64-row tile.
// acc[4][4] = 64 AGPRs; at the (256,4) tier that leaves 64 arch VGPRs.
// KEY: fragments are built/loaded ONE mt AT A TIME with their 4 MFMAs issued
// immediately -- peak VGPR live set ~60 (rounds 1-2 kept af[4]+bfw[4]+mv/iv
// live together -> 16 regs/thread spilled to scratch, +120-200 MB WRITE_SIZE).
// Operand-swapped MFMA: mfma(W_frag, h_frag) => lane's 4 acc regs are 4
// CONSECUTIVE cols of one row: row = 16*mt + l15, col = 64*w + 16*nt + 4*quad + r.
__global__ __launch_bounds__(256, 4) void fused_kernel(
    const float* __restrict__ featsA, const float* __restrict__ featsB,
    const float* __restrict__ mA, const float* __restrict__ mB,
    const float* __restrict__ bA, const float* __restrict__ bB,
    const float* __restrict__ Wv, const int* __restrict__ bidx,
    const char* __restrict__ ws, float* __restrict__ vpart, float* __restrict__ cpart,
    int tilesA, int nA, int nB)
{
  __shared__ __attribute__((aligned(16))) short ztile[64*264];   // h, bf16, stride 264
  __shared__ __attribute__((aligned(16))) float sred[64][4];
  __shared__ __attribute__((aligned(16))) float s2red[64][4];
  __shared__ __attribute__((aligned(16))) float vpw[64][4];

  const int tid  = threadIdx.x;
  const int wave = tid >> 6;
  const int lane = tid & 63;
  const int l15  = lane & 15;
  const int quad = lane >> 4;

  const bool isA = (blockIdx.x < (unsigned)tilesA);
  const int  tb  = isA ? blockIdx.x : (blockIdx.x - tilesA);
  const int  r0  = tb * 64;
  const int  nrows = isA ? nA : nB;
  const int  valid = min(64, nrows - r0);
  const float* feats = isA ? featsA : featsB;
  const float* meanp = isA ? mA : mB;
  const float* invp  = (const float*)(ws + (isA ? WS_INVA : WS_INVB));
  const float* biasp = isA ? bA : bB;
  const short* weT   = (const short*)(ws + (isA ? WS_WAT : WS_WBT2));
  const short* w2gT  = (const short*)(ws + (isA ? WS_W2GA : WS_W2GB));
  const float* c1p   = (const float*)(ws + (isA ? WS_C1A : WS_C1B));
  const float* c2p   = (const float*)(ws + (isA ? WS_C2A : WS_C2B));
  const int f       = isA ? 32 : 48;
  const int kstride = isA ? 32 : 64;
  const int ksteps  = isA ? 1 : 2;

  // ---- GEMM1: h = relu(norm(feats) @ W1 + b1), A-frags straight from global ----
  floatx4 acc1[4][4];
  #pragma unroll
  for (int mt = 0; mt < 4; mt++)
    #pragma unroll
    for (int nt = 0; nt < 4; nt++)
      acc1[mt][nt] = 0.0f;

  for (int kk = 0; kk < ksteps; kk++) {
    const int k0 = kk*32 + quad*8;
    const bool kvalid = (k0 < f);
    floatx4 mv0 = {0,0,0,0}, mv1 = {0,0,0,0}, iv0 = {1,1,1,1}, iv1 = {1,1,1,1};
    if (kvalid) {
      mv0 = *(const floatx4*)(meanp + k0);  mv1 = *(const floatx4*)(meanp + k0 + 4);
      iv0 = *(const floatx4*)(invp + k0);   iv1 = *(const floatx4*)(invp + k0 + 4);
    }
    short8 bfw[4];
    #pragma unroll
    for (int nt = 0; nt < 4; nt++)
      bfw[nt] = *(const short8*)(weT + (size_t)(64*wave + 16*nt + l15) * kstride + kk*32 + quad*8);
    #pragma unroll
    for (int mt = 0; mt < 4; mt++) {
      // build ONE A-fragment, use it, let it die
      short8 a = {0,0,0,0,0,0,0,0};
      int row = 16*mt + l15;
      if (kvalid && row < valid) {
        const float* fp = feats + (size_t)(r0 + row) * f + k0;
        floatx4 x0 = *(const floatx4*)fp;
        floatx4 x1 = *(const floatx4*)(fp + 4);
        #pragma unroll
        for (int e = 0; e < 4; e++) {
          float h0 = (x0[e] - mv0[e]) * iv0[e];
          h0 = fminf(fmaxf(h0, -5.0f), 5.0f);
          a[e] = f2bf(h0);
          float h1 = (x1[e] - mv1[e]) * iv1[e];
          h1 = fminf(fmaxf(h1, -5.0f), 5.0f);
          a[4+e] = f2bf(h1);
        }
      }
      #pragma unroll
      for (int nt = 0; nt < 4; nt++)
        acc1[mt][nt] = __builtin_amdgcn_mfma_f32_16x16x32_bf16(bfw[nt], a, acc1[mt][nt], 0, 0, 0);
    }
  }

  // ---- epilogue1: h=relu(.+b1) -> ztile (bf16, b64 packed) + per-row stats ----
  float sacc[4], s2acc[4];
  #pragma unroll
  for (int mt = 0; mt < 4; mt++) { sacc[mt] = 0.f; s2acc[mt] = 0.f; }

  #pragma unroll
  for (int nt = 0; nt < 4; nt++) {
    const int c0 = 64*wave + 16*nt + 4*quad;
    floatx4 b1v = *(const floatx4*)(biasp + c0);
    #pragma unroll
    for (int mt = 0; mt < 4; mt++) {
      short4v pk;
      #pragma unroll
      for (int r = 0; r < 4; r++) {
        float h = fmaxf(acc1[mt][nt][r] + b1v[r], 0.0f);
        sacc[mt] += h;
        s2acc[mt] = fmaf(h, h, s2acc[mt]);
        pk[r] = f2bf(h);
      }
      *(short4v*)(ztile + (16*mt + l15)*264 + c0) = pk;
    }
  }
  // reduce stats over the 4 quads (cols); rows are lane-local
  #pragma unroll
  for (int mt = 0; mt < 4; mt++) {
    float s = sacc[mt], s2 = s2acc[mt];
    s += __shfl_xor(s, 16, 64);  s2 += __shfl_xor(s2, 16, 64);
    s += __shfl_xor(s, 32, 64);  s2 += __shfl_xor(s2, 32, 64);
    if (lane < 16) {
      sred[16*mt + lane][wave] = s;
      s2red[16*mt + lane][wave] = s2;
    }
  }
  __syncthreads();

  // ---- per-row LN scalars (row = 16*mt + l15) ----
  float rsv[4], mrsv[4];
  #pragma unroll
  for (int mt = 0; mt < 4; mt++) {
    int row = 16*mt + l15;
    floatx4 sv  = *(const floatx4*)sred[row];
    floatx4 s2v = *(const floatx4*)s2red[row];
    float s  = sv[0] + sv[1] + sv[2] + sv[3];
    float s2 = s2v[0] + s2v[1] + s2v[2] + s2v[3];
    float mu  = s * (1.0f/256.0f);
    float var = fmaxf(s2 * (1.0f/256.0f) - mu*mu, 0.0f);
    float rs  = rsqrtf(var + 1e-5f);
    rsv[mt]  = rs;
    mrsv[mt] = mu * rs;
  }

  // ---- GEMM2: q = h @ (g*Wback), K=256 ----
  floatx4 acc2[4][4];
  #pragma unroll
  for (int mt = 0; mt < 4; mt++)
    #pragma unroll
    for (int nt = 0; nt < 4; nt++)
      acc2[mt][nt] = 0.0f;

  #pragma unroll 2
  for (int kk = 0; kk < 8; kk++) {
    short8 bf[4];
    #pragma unroll
    for (int nt = 0; nt < 4; nt++)
      bf[nt] = *(const short8*)(w2gT + (size_t)(64*wave + 16*nt + l15)*256 + kk*32 + quad*8);
    #pragma unroll
    for (int mt = 0; mt < 4; mt++) {
      short8 a = *(const short8*)(ztile + (16*mt + l15)*264 + kk*32 + quad*8);
      #pragma unroll
      for (int nt = 0; nt < 4; nt++)
        acc2[mt][nt] = __builtin_amdgcn_mfma_f32_16x16x32_bf16(bf[nt], a, acc2[mt][nt], 0, 0, 0);
    }
  }

  // ---- epilogue2: y = relu(rs*q - mu*rs*c1 + c2); v = y . Wv ----
  float pv[4] = {0.f, 0.f, 0.f, 0.f};
  #pragma unroll
  for (int nt = 0; nt < 4; nt++) {
    const int c0 = 64*wave + 16*nt + 4*quad;
    floatx4 c1v = *(const floatx4*)(c1p + c0);
    floatx4 c2v = *(const floatx4*)(c2p + c0);
    floatx4 wvv = *(const floatx4*)(Wv + c0);
    #pragma unroll
    for (int mt = 0; mt < 4; mt++) {
      float rs = rsv[mt], mrs = mrsv[mt];
      #pragma unroll
      for (int r = 0; r < 4; r++) {
        float t = fmaf(-mrs, c1v[r], c2v[r]);
        float y = fmaf(rs, acc2[mt][nt][r], t);
        y = fmaxf(y, 0.0f);
        pv[mt] = fmaf(y, wvv[r], pv[mt]);
      }
    }
  }
  #pragma unroll
  for (int mt = 0; mt < 4; mt++) {
    float p = pv[mt];
    p += __shfl_xor(p, 16, 64);
    p += __shfl_xor(p, 32, 64);
    if (lane < 16) vpw[16*mt + lane][wave] = p;
  }
  __syncthreads();

  // ---- scatter ----
  if (tid < valid) {
    floatx4 vv = *(const floatx4*)vpw[tid];
    float v = vv[0] + vv[1] + vv[2] + vv[3];
    int g = (isA ? r0 : (nA + r0)) + tid;
    int seg = bidx[g];
    int split = blockIdx.x & (NSPLIT - 1);
    atomicAdd(&vpart[split*NSEG + seg], v);
    atomicAdd(&cpart[split*NSEG + seg], 1.0f);
  }
}

__global__ void final_kernel(const float* __restrict__ vpart, const float* __restrict__ cpart,
                             const float* __restrict__ bv, float* __restrict__ out, int nseg) {
  int s = blockIdx.x * blockDim.x + threadIdx.x;
  if (s < nseg) {
    float a = 0.0f, c = 0.0f;
    #pragma unroll 8
    for (int i = 0; i < NSPLIT; i++) { a += vpart[i*NSEG + s]; c += cpart[i*NSEG + s]; }
    out[s] = a / fmaxf(c, 1.0f) + bv[0];
  }
}

extern "C" void kernel_launch(void* const* d_in, const int* in_sizes, int n_in,
                              void* d_out, int out_size, void* d_ws, size_t ws_size,
                              hipStream_t stream) {
  const float* featsA = (const float*)d_in[0];
  const float* featsB = (const float*)d_in[1];
  const float* mA     = (const float*)d_in[2];
  const float* sA     = (const float*)d_in[3];
  const float* mB     = (const float*)d_in[4];
  const float* sB     = (const float*)d_in[5];
  const float* WA     = (const float*)d_in[6];
  const float* bA     = (const float*)d_in[7];
  const float* gA     = (const float*)d_in[8];
  const float* betaA  = (const float*)d_in[9];
  const float* WB     = (const float*)d_in[10];
  const float* bB     = (const float*)d_in[11];
  const float* gB     = (const float*)d_in[12];
  const float* betaB  = (const float*)d_in[13];
  const float* Wback  = (const float*)d_in[14];
  const float* bback  = (const float*)d_in[15];
  const float* Wv     = (const float*)d_in[16];
  const float* bv     = (const float*)d_in[17];
  const int*   bidx   = (const int*)d_in[18];

  const int nA = in_sizes[0] / 32;
  const int nB = in_sizes[1] / 48;
  char* ws = (char*)d_ws;
  float* vpart = (float*)(ws + WS_VPART);
  float* cpart = (float*)(ws + WS_CPART);
  float* out = (float*)d_out;

  prep_kernel<<<256, 256, 0, stream>>>(WA, WB, Wback, gA, betaA, gB, betaB,
                                       bback, sA, sB, ws);

  const int tilesA = (nA + 63) / 64;
  const int tilesB = (nB + 63) / 64;
  fused_kernel<<<tilesA + tilesB, 256, 0, stream>>>(
      featsA, featsB, mA, mB, bA, bB, Wv, bidx, ws, vpart, cpart, tilesA, nA, nB);

  final_kernel<<<(out_size + 255) / 256, 256, 0, stream>>>(vpart, cpart, bv, out, out_size);
}